// Round 7
// baseline (79.563 us; speedup 1.0000x reference)
//
#include <hip/hip_runtime.h>
#include <math.h>

#define D    2048
#define NB   8
#define BSZ  16
#define ZZ   64
#define HH   256
#define CC   10
#define PCHUNK 128           // pairs per block chunk
#define GSPLIT 128           // 16384 / PCHUNK
#define KC     8             // column chunks of 256 cols
#define NBLK (KC * GSPLIT)   // 1024 k_main blocks

// ---------------------------------------------------------------------------
// K1 (k_coeff): ONE block, 512 threads. Hypernet -> coeffs^T[NB][BSZ] in ws.
// Writes attn_map = 1.0 exactly (softmax over a singleton axis).
// ---------------------------------------------------------------------------
__global__ __launch_bounds__(512) void k_coeff(
    const int* __restrict__ seeds, const float* __restrict__ semb,
    const float* __restrict__ statc,
    const float* __restrict__ hw1, const float* __restrict__ hb1,
    const float* __restrict__ hw2, const float* __restrict__ hb2,
    float* __restrict__ coeffT, float* __restrict__ out)
{
    int t = threadIdx.x;
    __shared__ float zs[BSZ][ZZ];          // 4 KB
    __shared__ float hp[2][BSZ][HH];       // 32 KB (split-u partials)
    __shared__ float hs[BSZ][258];         // padded
    __shared__ float lgs[BSZ][NB];

    for (int e = t; e < BSZ * ZZ; e += 512) {
        int b = e >> 6, u = e & (ZZ - 1);
        zs[b][u] = semb[seeds[b] * ZZ + u];
    }
    __syncthreads();

    {   // split-u: threads (uh, col) each accumulate 32 u's for all 16 b
        int col = t & 255, uh = t >> 8;
        float acc[BSZ];
        #pragma unroll
        for (int b = 0; b < BSZ; ++b) acc[b] = 0.f;
        #pragma unroll 8
        for (int u = 0; u < 32; ++u) {
            float w = hw1[(uh * 32 + u) * HH + col];
            #pragma unroll
            for (int b = 0; b < BSZ; ++b) acc[b] = fmaf(zs[b][uh * 32 + u], w, acc[b]);
        }
        #pragma unroll
        for (int b = 0; b < BSZ; ++b) hp[uh][b][col] = acc[b];
    }
    __syncthreads();

    if (t < HH) {
        float bias = hb1[t];
        #pragma unroll
        for (int b = 0; b < BSZ; ++b)
            hs[b][t] = fmaxf(hp[0][b][t] + hp[1][b][t] + bias, 0.f);
    }
    __syncthreads();

    {   // logits: t = b*32 + c*4 + q ; u = q + 4*uu (interleaved quarter-split)
        int b = t >> 5, c = (t >> 2) & 7, q = t & 3;
        float s = (q == 0) ? hb2[c] : 0.f;
        #pragma unroll 8
        for (int uu = 0; uu < 64; ++uu) {
            int u = q + 4 * uu;
            s = fmaf(hs[b][u], hw2[u * NB + c], s);
        }
        s += __shfl_xor(s, 1);
        s += __shfl_xor(s, 2);
        if (q == 0) lgs[b][c] = s;
    }
    __syncthreads();

    if (t < BSZ) {
        int b = t;
        float m = lgs[b][0];
        #pragma unroll
        for (int i = 1; i < NB; ++i) m = fmaxf(m, lgs[b][i]);
        float e[NB], s = 0.f;
        #pragma unroll
        for (int i = 0; i < NB; ++i) { e[i] = expf(lgs[b][i] - m); s += e[i]; }
        float m2 = statc[0];
        #pragma unroll
        for (int i = 1; i < NB; ++i) m2 = fmaxf(m2, statc[i]);
        float e2[NB], s2 = 0.f;
        #pragma unroll
        for (int i = 0; i < NB; ++i) { e2[i] = expf(statc[i] - m2); s2 += e2[i]; }
        #pragma unroll
        for (int i = 0; i < NB; ++i) coeffT[i * BSZ + b] = e[i] / s + e2[i] / s2;
        out[BSZ * CC + b] = 1.0f;          // attn_map == 1 exactly
    }
}

// ---------------------------------------------------------------------------
// K2 (k_main): for block (kc,g):
//   s[b][k] = cf[b] * sum_{p in g-chunk(128)} feat[b][j(p)] * wv[p][k]
//   plog[(b*CC+c)][blk] = sum_k s[b][k]*cw[k][c]
// CRITICAL: every acc[] index is compile-time constant (both reduce loops
// fully unrolled). R1-R6 indexed acc[round*4+bb] with runtime `round`,
// which forced the 64-float accumulator into SCRATCH (VGPR_Count=64 in R5
// profile == acc alone) -> ~134MB of private-memory round-trips.
// ---------------------------------------------------------------------------
__global__ __launch_bounds__(512, 4) void k_main(
    const float* __restrict__ wv, const float* __restrict__ feat,
    const float* __restrict__ coeffT, const float* __restrict__ cw,
    float* __restrict__ plog)
{
    int kc   = blockIdx.x;                                    // 0..7
    int g    = blockIdx.y;                                    // 0..127
    int blk  = g * KC + kc;                                   // 0..1023
    int t    = threadIdx.x;
    int wave = t >> 6;
    int lane = t & 63;
    int col  = kc * 256 + lane * 4;

    __shared__ float scratch[16 * 264];  // ft view: [p][b] (p*16+b), 2048 fl
                                         // vred view: [b][k] (b*264+k), padded
    __shared__ float4 sh[4][8][64];      // 32 KB reduce buffer
    float* ft = scratch;

    {   // stage feat slice transposed: ft[p*16+b] = feat[b][jbase+p]
        int jbase = (g & 15) * PCHUNK;
        int b = t & 15, j = t >> 4;      // j in 0..31 (+32 per round)
        #pragma unroll
        for (int r = 0; r < 4; ++r)
            ft[t + 512 * r] = feat[b * D + jbase + j + 32 * r];
    }
    __syncthreads();

    float4 acc[BSZ];
    #pragma unroll
    for (int b = 0; b < BSZ; ++b) acc[b] = make_float4(0.f, 0.f, 0.f, 0.f);

    int pair0 = wave * 16;               // 16 pairs per wave
    const float* wp = wv + ((size_t)(g * PCHUNK + pair0)) * D + col;
    const float* fp = ft + pair0 * BSZ;

    #pragma unroll 8
    for (int it = 0; it < 16; ++it) {
        const float4 w = *reinterpret_cast<const float4*>(wp + (size_t)it * D);
        const float4* ap4 = reinterpret_cast<const float4*>(fp + it * BSZ);
        float4 a0 = ap4[0], a1 = ap4[1], a2 = ap4[2], a3 = ap4[3];  // broadcast b128
#define FMA4(ACC, A) \
        ACC.x = fmaf(A, w.x, ACC.x); ACC.y = fmaf(A, w.y, ACC.y); \
        ACC.z = fmaf(A, w.z, ACC.z); ACC.w = fmaf(A, w.w, ACC.w);
        FMA4(acc[0],  a0.x) FMA4(acc[1],  a0.y) FMA4(acc[2],  a0.z) FMA4(acc[3],  a0.w)
        FMA4(acc[4],  a1.x) FMA4(acc[5],  a1.y) FMA4(acc[6],  a1.z) FMA4(acc[7],  a1.w)
        FMA4(acc[8],  a2.x) FMA4(acc[9],  a2.y) FMA4(acc[10], a2.z) FMA4(acc[11], a2.w)
        FMA4(acc[12], a3.x) FMA4(acc[13], a3.y) FMA4(acc[14], a3.z) FMA4(acc[15], a3.w)
#undef FMA4
    }

    // cross-wave reduce into vred (aliases ft; barriers order the phases).
    // BOTH loops fully unrolled -> acc[] indices static -> acc stays in VGPRs.
    const float* cfp = coeffT + (g >> 4) * BSZ;
    float* vred = scratch;               // [b][k] stride 264
    #pragma unroll
    for (int round = 0; round < 4; ++round) {
        #pragma unroll
        for (int bb = 0; bb < 4; ++bb)
            sh[bb][wave][lane] = acc[round * 4 + bb];
        __syncthreads();
        if (wave < 4) {
            float4 s = sh[wave][0][lane];
            #pragma unroll
            for (int sw = 1; sw < 8; ++sw) {
                float4 x = sh[wave][sw][lane];
                s.x += x.x; s.y += x.y; s.z += x.z; s.w += x.w;
            }
            int b = round * 4 + wave;
            float cf = cfp[b];
            s.x *= cf; s.y *= cf; s.z *= cf; s.w *= cf;
            *reinterpret_cast<float4*>(&vred[b * 264 + lane * 4]) = s;
        }
        __syncthreads();
    }

    // logits phase: t<256 -> (b = t>>4, q = t&15), k = q + 16*i
    if (t < 256) {
        int b = t >> 4, q = t & 15;
        const float* vp = vred + b * 264;
        const float* cp = cw + ((size_t)(kc * 256 + q)) * CC;
        float p[CC];
        #pragma unroll
        for (int c = 0; c < CC; ++c) p[c] = 0.f;
        #pragma unroll 4
        for (int i = 0; i < 16; ++i) {
            float vv = vp[q + 16 * i];
            const float* cr = cp + 160 * i;
            #pragma unroll
            for (int c = 0; c < CC; ++c) p[c] = fmaf(vv, cr[c], p[c]);
        }
        #pragma unroll
        for (int c = 0; c < CC; ++c) {
            p[c] += __shfl_xor(p[c], 1);
            p[c] += __shfl_xor(p[c], 2);
            p[c] += __shfl_xor(p[c], 4);
            p[c] += __shfl_xor(p[c], 8);
        }
        if (q == 0) {
            #pragma unroll
            for (int c = 0; c < CC; ++c)
                plog[(size_t)(b * CC + c) * NBLK + blk] = p[c];
        }
    }
}

// ---------------------------------------------------------------------------
// K3 (k_fin): logits[bc] = sum_{blk} plog[bc][blk] + cb[c].
// One block, 640 threads = 160 bc x 4 sub; shfl-reduce the 4 subs.
// ---------------------------------------------------------------------------
__global__ __launch_bounds__(640) void k_fin(
    const float* __restrict__ plog, const float* __restrict__ cb,
    float* __restrict__ out)
{
    int t = threadIdx.x;
    int bc = t >> 2, s = t & 3;
    const float* p = plog + (size_t)bc * NBLK;
    float a0 = 0.f, a1 = 0.f;
    #pragma unroll 8
    for (int r = 0; r < NBLK / 8; ++r) {
        a0 += p[s + 8 * r];
        a1 += p[s + 4 + 8 * r];
    }
    float a = a0 + a1;
    a += __shfl_xor(a, 1);
    a += __shfl_xor(a, 2);
    if (s == 0) {
        int c = bc - (bc / CC) * CC;
        out[bc] = a + cb[c];
    }
}

// ---------------------------------------------------------------------------
extern "C" void kernel_launch(void* const* d_in, const int* in_sizes, int n_in,
                              void* d_out, int out_size, void* d_ws, size_t ws_size,
                              hipStream_t stream)
{
    const float* feat  = (const float*)d_in[0];
    const int*   seeds = (const int*)  d_in[1];
    const float* semb  = (const float*)d_in[2];
    const float* statc = (const float*)d_in[3];
    const float* hw1   = (const float*)d_in[4];
    const float* hb1   = (const float*)d_in[5];
    const float* hw2   = (const float*)d_in[6];
    const float* hb2   = (const float*)d_in[7];
    // d_in[8] = wq, d_in[9] = wk: DEAD — attn softmax over a singleton axis is
    // identically 1, so pooled == v and q,k never reach the output.
    const float* wv    = (const float*)d_in[10];
    const float* cw    = (const float*)d_in[11];
    const float* cb    = (const float*)d_in[12];
    float* out = (float*)d_out;

    float* coeffT = (float*)d_ws;                     // 128 floats (pad 256)
    float* plog   = coeffT + 256;                     // 160*1024 fl = 640 KiB

    hipLaunchKernelGGL(k_coeff, dim3(1), dim3(512), 0, stream,
                       seeds, semb, statc, hw1, hb1, hw2, hb2, coeffT, out);
    hipLaunchKernelGGL(k_main, dim3(KC, GSPLIT), dim3(512), 0, stream,
                       wv, feat, coeffT, cw, plog);
    hipLaunchKernelGGL(k_fin, dim3(1), dim3(640), 0, stream,
                       plog, cb, out);
}

// Round 8
// 62.483 us; speedup vs baseline: 1.2734x; 1.2734x over previous
//
#include <hip/hip_runtime.h>
#include <math.h>

#define D    2048
#define NB   8
#define BSZ  16
#define ZZ   64
#define HH   256
#define CC   10
#define PCHUNK 256           // pairs per block chunk
#define GSPLIT 64            // 16384 / PCHUNK
#define KC     8             // column chunks of 256 cols
#define NBLK (KC * GSPLIT)   // 512 k_main blocks

// ---------------------------------------------------------------------------
// K1 (k_coeff): ONE block, 512 threads. Hypernet -> coeffs^T[NB][BSZ] in ws.
// Writes attn_map = 1.0 exactly (softmax over a singleton axis).
// ---------------------------------------------------------------------------
__global__ __launch_bounds__(512) void k_coeff(
    const int* __restrict__ seeds, const float* __restrict__ semb,
    const float* __restrict__ statc,
    const float* __restrict__ hw1, const float* __restrict__ hb1,
    const float* __restrict__ hw2, const float* __restrict__ hb2,
    float* __restrict__ coeffT, float* __restrict__ out)
{
    int t = threadIdx.x;
    __shared__ float zs[BSZ][ZZ];          // 4 KB
    __shared__ float hp[2][BSZ][HH];       // 32 KB (split-u partials)
    __shared__ float hs[BSZ][258];         // padded
    __shared__ float lgs[BSZ][NB];

    for (int e = t; e < BSZ * ZZ; e += 512) {
        int b = e >> 6, u = e & (ZZ - 1);
        zs[b][u] = semb[seeds[b] * ZZ + u];
    }
    __syncthreads();

    {   // split-u: threads (uh, col) each accumulate 32 u's for all 16 b
        int col = t & 255, uh = t >> 8;
        float acc[BSZ];
        #pragma unroll
        for (int b = 0; b < BSZ; ++b) acc[b] = 0.f;
        #pragma unroll 8
        for (int u = 0; u < 32; ++u) {
            float w = hw1[(uh * 32 + u) * HH + col];
            #pragma unroll
            for (int b = 0; b < BSZ; ++b) acc[b] = fmaf(zs[b][uh * 32 + u], w, acc[b]);
        }
        #pragma unroll
        for (int b = 0; b < BSZ; ++b) hp[uh][b][col] = acc[b];
    }
    __syncthreads();

    if (t < HH) {
        float bias = hb1[t];
        #pragma unroll
        for (int b = 0; b < BSZ; ++b)
            hs[b][t] = fmaxf(hp[0][b][t] + hp[1][b][t] + bias, 0.f);
    }
    __syncthreads();

    {   // logits: t = b*32 + c*4 + q ; u = q + 4*uu (interleaved quarter-split)
        int b = t >> 5, c = (t >> 2) & 7, q = t & 3;
        float s = (q == 0) ? hb2[c] : 0.f;
        #pragma unroll 8
        for (int uu = 0; uu < 64; ++uu) {
            int u = q + 4 * uu;
            s = fmaf(hs[b][u], hw2[u * NB + c], s);
        }
        s += __shfl_xor(s, 1);
        s += __shfl_xor(s, 2);
        if (q == 0) lgs[b][c] = s;
    }
    __syncthreads();

    if (t < BSZ) {
        int b = t;
        float m = lgs[b][0];
        #pragma unroll
        for (int i = 1; i < NB; ++i) m = fmaxf(m, lgs[b][i]);
        float e[NB], s = 0.f;
        #pragma unroll
        for (int i = 0; i < NB; ++i) { e[i] = expf(lgs[b][i] - m); s += e[i]; }
        float m2 = statc[0];
        #pragma unroll
        for (int i = 1; i < NB; ++i) m2 = fmaxf(m2, statc[i]);
        float e2[NB], s2 = 0.f;
        #pragma unroll
        for (int i = 0; i < NB; ++i) { e2[i] = expf(statc[i] - m2); s2 += e2[i]; }
        #pragma unroll
        for (int i = 0; i < NB; ++i) coeffT[i * BSZ + b] = e[i] / s + e2[i] / s2;
        out[BSZ * CC + b] = 1.0f;          // attn_map == 1 exactly
    }
}

// ---------------------------------------------------------------------------
// K2 (k_main): for block (kc,g):
//   s[b][k] = cf[b] * sum_{p in g-chunk(256)} feat[b][j(p)] * wv[p][k]
//   plog[(b*CC+c)][blk] = sum_k s[b][k]*cw[k][c]
// __launch_bounds__(512, 2): R6/R7 used (512,4) -> 128-reg unified budget
// -> 64 arch VGPR + 64 AGPR(acc) -> only ~1-2 global loads in flight ->
// latency-bound at 1.2 TB/s (R7 profile: VGPR=64, VALUBusy 14%, hbm 14.7%).
// 256-reg budget lets the unroll-8 loop keep ~8 wv loads in flight.
// ---------------------------------------------------------------------------
__global__ __launch_bounds__(512, 2) void k_main(
    const float* __restrict__ wv, const float* __restrict__ feat,
    const float* __restrict__ coeffT, const float* __restrict__ cw,
    float* __restrict__ plog)
{
    int kc   = blockIdx.x;                                    // 0..7
    int g    = blockIdx.y;                                    // 0..63
    int blk  = g * KC + kc;                                   // 0..511
    int t    = threadIdx.x;
    int wave = t >> 6;
    int lane = t & 63;
    int col  = kc * 256 + lane * 4;

    __shared__ float scratch[16 * 264];  // ft view: [p][b] (p*16+b), 4096 fl
                                         // vred view: [b][k] (b*264+k), padded
    __shared__ float4 sh[4][8][64];      // 32 KB reduce buffer
    float* ft = scratch;

    {   // stage feat slice transposed: ft[p*16+b] = feat[b][jbase+p]
        int jbase = (g & 7) * PCHUNK;
        int b = t & 15, j = t >> 4;      // j in 0..31 (+32 per round)
        #pragma unroll
        for (int r = 0; r < 8; ++r)
            ft[t + 512 * r] = feat[b * D + jbase + j + 32 * r];
    }
    __syncthreads();

    float4 acc[BSZ];
    #pragma unroll
    for (int b = 0; b < BSZ; ++b) acc[b] = make_float4(0.f, 0.f, 0.f, 0.f);

    int pair0 = wave * 32;               // 32 pairs per wave
    const float* wp = wv + ((size_t)(g * PCHUNK + pair0)) * D + col;
    const float* fp = ft + pair0 * BSZ;

    #pragma unroll 8
    for (int it = 0; it < 32; ++it) {
        const float4 w = *reinterpret_cast<const float4*>(wp + (size_t)it * D);
        const float4* ap4 = reinterpret_cast<const float4*>(fp + it * BSZ);
        float4 a0 = ap4[0], a1 = ap4[1], a2 = ap4[2], a3 = ap4[3];  // broadcast b128
#define FMA4(ACC, A) \
        ACC.x = fmaf(A, w.x, ACC.x); ACC.y = fmaf(A, w.y, ACC.y); \
        ACC.z = fmaf(A, w.z, ACC.z); ACC.w = fmaf(A, w.w, ACC.w);
        FMA4(acc[0],  a0.x) FMA4(acc[1],  a0.y) FMA4(acc[2],  a0.z) FMA4(acc[3],  a0.w)
        FMA4(acc[4],  a1.x) FMA4(acc[5],  a1.y) FMA4(acc[6],  a1.z) FMA4(acc[7],  a1.w)
        FMA4(acc[8],  a2.x) FMA4(acc[9],  a2.y) FMA4(acc[10], a2.z) FMA4(acc[11], a2.w)
        FMA4(acc[12], a3.x) FMA4(acc[13], a3.y) FMA4(acc[14], a3.z) FMA4(acc[15], a3.w)
#undef FMA4
    }

    // cross-wave reduce into vred (aliases ft; barriers order the phases).
    // Fully unrolled -> all acc[] indices static -> acc stays in registers.
    const float* cfp = coeffT + (g >> 3) * BSZ;
    float* vred = scratch;               // [b][k] stride 264
    #pragma unroll
    for (int round = 0; round < 4; ++round) {
        #pragma unroll
        for (int bb = 0; bb < 4; ++bb)
            sh[bb][wave][lane] = acc[round * 4 + bb];
        __syncthreads();
        if (wave < 4) {
            float4 s = sh[wave][0][lane];
            #pragma unroll
            for (int sw = 1; sw < 8; ++sw) {
                float4 x = sh[wave][sw][lane];
                s.x += x.x; s.y += x.y; s.z += x.z; s.w += x.w;
            }
            int b = round * 4 + wave;
            float cf = cfp[b];
            s.x *= cf; s.y *= cf; s.z *= cf; s.w *= cf;
            *reinterpret_cast<float4*>(&vred[b * 264 + lane * 4]) = s;
        }
        __syncthreads();
    }

    // logits phase: t<256 -> (b = t>>4, q = t&15), k = q + 16*i
    if (t < 256) {
        int b = t >> 4, q = t & 15;
        const float* vp = vred + b * 264;
        const float* cp = cw + ((size_t)(kc * 256 + q)) * CC;
        float p[CC];
        #pragma unroll
        for (int c = 0; c < CC; ++c) p[c] = 0.f;
        #pragma unroll 4
        for (int i = 0; i < 16; ++i) {
            float vv = vp[q + 16 * i];
            const float* cr = cp + 160 * i;
            #pragma unroll
            for (int c = 0; c < CC; ++c) p[c] = fmaf(vv, cr[c], p[c]);
        }
        #pragma unroll
        for (int c = 0; c < CC; ++c) {
            p[c] += __shfl_xor(p[c], 1);
            p[c] += __shfl_xor(p[c], 2);
            p[c] += __shfl_xor(p[c], 4);
            p[c] += __shfl_xor(p[c], 8);
        }
        if (q == 0) {
            #pragma unroll
            for (int c = 0; c < CC; ++c)
                plog[(size_t)(b * CC + c) * NBLK + blk] = p[c];
        }
    }
}

// ---------------------------------------------------------------------------
// K3 (k_fin): logits[bc] = sum_{blk} plog[bc][blk] + cb[c].
// One block, 640 threads = 160 bc x 4 sub; shfl-reduce the 4 subs.
// ---------------------------------------------------------------------------
__global__ __launch_bounds__(640) void k_fin(
    const float* __restrict__ plog, const float* __restrict__ cb,
    float* __restrict__ out)
{
    int t = threadIdx.x;
    int bc = t >> 2, s = t & 3;
    const float* p = plog + (size_t)bc * NBLK;
    float a0 = 0.f, a1 = 0.f;
    #pragma unroll 8
    for (int r = 0; r < NBLK / 8; ++r) {
        a0 += p[s + 8 * r];
        a1 += p[s + 4 + 8 * r];
    }
    float a = a0 + a1;
    a += __shfl_xor(a, 1);
    a += __shfl_xor(a, 2);
    if (s == 0) {
        int c = bc - (bc / CC) * CC;
        out[bc] = a + cb[c];
    }
}

// ---------------------------------------------------------------------------
extern "C" void kernel_launch(void* const* d_in, const int* in_sizes, int n_in,
                              void* d_out, int out_size, void* d_ws, size_t ws_size,
                              hipStream_t stream)
{
    const float* feat  = (const float*)d_in[0];
    const int*   seeds = (const int*)  d_in[1];
    const float* semb  = (const float*)d_in[2];
    const float* statc = (const float*)d_in[3];
    const float* hw1   = (const float*)d_in[4];
    const float* hb1   = (const float*)d_in[5];
    const float* hw2   = (const float*)d_in[6];
    const float* hb2   = (const float*)d_in[7];
    // d_in[8] = wq, d_in[9] = wk: DEAD — attn softmax over a singleton axis is
    // identically 1, so pooled == v and q,k never reach the output.
    const float* wv    = (const float*)d_in[10];
    const float* cw    = (const float*)d_in[11];
    const float* cb    = (const float*)d_in[12];
    float* out = (float*)d_out;

    float* coeffT = (float*)d_ws;                     // 128 floats (pad 256)
    float* plog   = coeffT + 256;                     // 160*512 fl = 320 KiB

    hipLaunchKernelGGL(k_coeff, dim3(1), dim3(512), 0, stream,
                       seeds, semb, statc, hw1, hb1, hw2, hb2, coeffT, out);
    hipLaunchKernelGGL(k_main, dim3(KC, GSPLIT), dim3(512), 0, stream,
                       wv, feat, coeffT, cw, plog);
    hipLaunchKernelGGL(k_fin, dim3(1), dim3(640), 0, stream,
                       plog, cb, out);
}